// Round 1
// baseline (57.069 us; speedup 1.0000x reference)
//
#include <hip/hip_runtime.h>
#include <math.h>

#define TEMP_INV (1.0f / 0.07f)

__device__ __forceinline__ float wave_reduce_sum(float v) {
    #pragma unroll
    for (int off = 32; off; off >>= 1) v += __shfl_down(v, off);
    return v;
}

__device__ __forceinline__ float wave_reduce_max(float v) {
    #pragma unroll
    for (int off = 32; off; off >>= 1) v = fmaxf(v, __shfl_down(v, off));
    return v;
}

// One wave per row: inv_norm(anchor) and pos_sim = <a_hat, p_hat>/T
__global__ void k_rows(const float* __restrict__ A, const float* __restrict__ P,
                       float* __restrict__ inv_na, float* __restrict__ pos_sim, int B) {
    int wave = (int)((blockIdx.x * blockDim.x + threadIdx.x) >> 6);
    int lane = threadIdx.x & 63;
    if (wave >= B) return;
    const float4 a = reinterpret_cast<const float4*>(A + (size_t)wave * 256)[lane];
    const float4 p = reinterpret_cast<const float4*>(P + (size_t)wave * 256)[lane];
    float sa = a.x * a.x + a.y * a.y + a.z * a.z + a.w * a.w;
    float sp = p.x * p.x + p.y * p.y + p.z * p.z + p.w * p.w;
    float dp = a.x * p.x + a.y * p.y + a.z * p.z + a.w * p.w;
    sa = wave_reduce_sum(sa);
    sp = wave_reduce_sum(sp);
    dp = wave_reduce_sum(dp);
    if (lane == 0) {
        float ia = 1.0f / fmaxf(sqrtf(sa), 1e-12f);
        float ip = 1.0f / fmaxf(sqrtf(sp), 1e-12f);
        inv_na[wave]  = ia;
        pos_sim[wave] = dp * ia * ip * TEMP_INV;
    }
}

// One wave per negative: neg_sim[j] = <a_hat[idx[j]], n_hat[j]>/T
__global__ void k_neg(const float* __restrict__ A, const float* __restrict__ Ng,
                      const int* __restrict__ idx, const float* __restrict__ inv_na,
                      float* __restrict__ neg_sim, int N) {
    int wave = (int)((blockIdx.x * blockDim.x + threadIdx.x) >> 6);
    int lane = threadIdx.x & 63;
    if (wave >= N) return;
    int b = idx[wave];
    const float4 n4 = reinterpret_cast<const float4*>(Ng + (size_t)wave * 256)[lane];
    const float4 a4 = reinterpret_cast<const float4*>(A + (size_t)b * 256)[lane];
    float sn = n4.x * n4.x + n4.y * n4.y + n4.z * n4.z + n4.w * n4.w;
    float dp = a4.x * n4.x + a4.y * n4.y + a4.z * n4.z + a4.w * n4.w;
    sn = wave_reduce_sum(sn);
    dp = wave_reduce_sum(dp);
    if (lane == 0) {
        float in_ = 1.0f / fmaxf(sqrtf(sn), 1e-12f);
        neg_sim[wave] = dp * inv_na[b] * in_ * TEMP_INV;
    }
}

// One wave (block of 64) per batch row: segment max + log-sum-exp
__global__ void k_seg(const int* __restrict__ idx, const float* __restrict__ neg_sim,
                      const float* __restrict__ pos_sim, float* __restrict__ loss_i,
                      float* __restrict__ corr, int N) {
    int b = blockIdx.x;
    int lane = threadIdx.x;  // blockDim.x == 64

    // lower_bound(idx, b) and lower_bound(idx, b+1) — idx is sorted
    int lo = 0, hi = N;
    while (lo < hi) { int mid = (lo + hi) >> 1; if (idx[mid] < b) lo = mid + 1; else hi = mid; }
    int s = lo;
    lo = s; hi = N;
    while (lo < hi) { int mid = (lo + hi) >> 1; if (idx[mid] < b + 1) lo = mid + 1; else hi = mid; }
    int e = lo;

    float ps = pos_sim[b];
    if (e == s) {  // empty segment: loss skipped, correct = false
        if (lane == 0) { loss_i[b] = 0.0f; corr[b] = 0.0f; }
        return;
    }

    float mx = -INFINITY;
    for (int j = s + lane; j < e; j += 64) mx = fmaxf(mx, neg_sim[j]);
    mx = wave_reduce_max(mx);
    mx = __shfl(mx, 0);

    float m = fmaxf(ps, mx);
    float se = 0.0f;
    for (int j = s + lane; j < e; j += 64) se += expf(neg_sim[j] - m);
    se = wave_reduce_sum(se);

    if (lane == 0) {
        se += expf(ps - m);
        loss_i[b] = -ps + m + logf(se);
        corr[b]   = (ps > mx) ? 1.0f : 0.0f;
    }
}

// Single-block deterministic reduce -> out[0]=loss, out[1]=accuracy
__global__ void k_final(const float* __restrict__ loss_i, const float* __restrict__ corr,
                        float* __restrict__ out, int B) {
    __shared__ float sl[256];
    __shared__ float sc[256];
    float l = 0.0f, c = 0.0f;
    for (int i = threadIdx.x; i < B; i += 256) { l += loss_i[i]; c += corr[i]; }
    sl[threadIdx.x] = l; sc[threadIdx.x] = c;
    __syncthreads();
    for (int s = 128; s; s >>= 1) {
        if ((int)threadIdx.x < s) {
            sl[threadIdx.x] += sl[threadIdx.x + s];
            sc[threadIdx.x] += sc[threadIdx.x + s];
        }
        __syncthreads();
    }
    if (threadIdx.x == 0) {
        out[0] = sl[0] / (float)B;
        out[1] = sc[0] / (float)B;
    }
}

extern "C" void kernel_launch(void* const* d_in, const int* in_sizes, int n_in,
                              void* d_out, int out_size, void* d_ws, size_t ws_size,
                              hipStream_t stream) {
    const float* anchor    = (const float*)d_in[0];
    const float* positive  = (const float*)d_in[1];
    const float* negatives = (const float*)d_in[2];
    const int*   idx       = (const int*)d_in[3];

    const int D = 256;
    const int B = in_sizes[0] / D;   // 4096
    const int N = in_sizes[2] / D;   // 131072

    float* ws       = (float*)d_ws;
    float* neg_sim  = ws;            // N
    float* inv_na   = ws + N;        // B
    float* pos_sim  = ws + N + B;    // B
    float* loss_i   = ws + N + 2 * B; // B
    float* corr     = ws + N + 3 * B; // B

    float* out = (float*)d_out;

    // K1: row stats (4 waves per 256-thread block)
    k_rows<<<(B + 3) / 4, 256, 0, stream>>>(anchor, positive, inv_na, pos_sim, B);

    // K2: neg sims (4 waves per 256-thread block)
    k_neg<<<(N + 3) / 4, 256, 0, stream>>>(anchor, negatives, idx, inv_na, neg_sim, N);

    // K3: per-segment LSE (one wave per b)
    k_seg<<<B, 64, 0, stream>>>(idx, neg_sim, pos_sim, loss_i, corr, N);

    // K4: final deterministic reduce
    k_final<<<1, 256, 0, stream>>>(loss_i, corr, out, B);
}